// Round 1
// baseline (12334.415 us; speedup 1.0000x reference)
//
#include <hip/hip_runtime.h>
#include <math.h>

#define TSTEPS 512
// ws layout in floats:
//  wti : [1024 cols][1024 s][2] interleaved {w_u[s][c], w_r[s][c]}   @ 0        (2097152)
//  h   : [1024 s][64 b]                                              @ 2097152  (65536)
//  th0 : [1024 s][64 b]                                              @ 2162688  (65536)
//  th1 : [1024 s][64 b]                                              @ 2228224  (65536)
#define WTI_OFF 0
#define H_OFF   2097152
#define TH_OFF  2162688
#define TH_SIZE 65536

__global__ __launch_bounds__(256) void ugrnn_setup(
    const float* __restrict__ h_init,
    const float* __restrict__ w_u,
    const float* __restrict__ w_r,
    float* __restrict__ ws,
    float* __restrict__ out)
{
    const int nthr = 512 * 256;
    int tid = blockIdx.x * 256 + threadIdx.x;

    // 1) zero the output (atomics accumulate into it later)
    float4* o4 = (float4*)out;
    for (int i = tid; i < (TSTEPS * 64 * 128) / 4; i += nthr)
        o4[i] = make_float4(0.f, 0.f, 0.f, 0.f);

    // 2) build interleaved transposed weights: wti[c][s] = {w_u[s][c], w_r[s][c]}
    //    consecutive tid -> consecutive s for fixed c => coalesced writes
    float* wti = ws + WTI_OFF;
    for (int idx = tid; idx < 1024 * 1024; idx += nthr) {
        int s = idx & 1023;
        int c = idx >> 10;
        float2 v = make_float2(w_u[s * 1024 + c], w_r[s * 1024 + c]);
        *(float2*)(wti + (size_t)c * 2048 + s * 2) = v;
    }

    // 3) h (transposed to [s][b]) and th0 = tanh(h)
    float* h   = ws + H_OFF;
    float* th0 = ws + TH_OFF;
    if (tid < 65536) {
        int s = tid >> 6, b = tid & 63;
        float v = h_init[b * 1024 + s];
        h[tid]   = v;
        th0[tid] = tanhf(v);
    }
}

__device__ __forceinline__ void red4(float4& v)
{
    v.x += __shfl_down(v.x, 32); v.y += __shfl_down(v.y, 32);
    v.z += __shfl_down(v.z, 32); v.w += __shfl_down(v.w, 32);
    v.x += __shfl_down(v.x, 16); v.y += __shfl_down(v.y, 16);
    v.z += __shfl_down(v.z, 16); v.w += __shfl_down(v.w, 16);
}

// grid: 256 blocks x 512 threads. Step t (t in [0, TSTEPS]):
//   reads th_cur = tanh(h_t); computes gate pre-acts -> h_{t+1}, th_next (t < TSTEPS)
//   accumulates err[t-1] = th_cur @ w_o^T + b_o - x[t-1]  (t >= 1)
__global__ __launch_bounds__(512) void ugrnn_step(
    const float* __restrict__ x,
    const float* __restrict__ w_o,
    const float* __restrict__ b_o,
    const float* __restrict__ b_u,
    const float* __restrict__ b_r,
    float* __restrict__ ws,
    float* __restrict__ out,
    int t)
{
    const float* wti = ws + WTI_OFF;
    float* h   = ws + H_OFF;
    float* thc = ws + TH_OFF + (t & 1) * TH_SIZE;
    float* thn = ws + TH_OFF + ((t + 1) & 1) * TH_SIZE;

    const int wib  = threadIdx.x >> 6;      // 0..7
    const int lane = threadIdx.x & 63;
    const int col  = blockIdx.x * 4 + (wib & 3);   // state column 0..1023
    const int half = wib >> 2;                      // s-range half
    const int o    = col >> 3;                      // output column 0..127
    const int oc0  = (col & 7) * 16;                // local chunk where o-slice begins

    const int r = lane >> 4;                        // s residue 0..3 within chunk

    const float*  thbase = thc + half * 32768;                       // 128 chunks * 256 floats
    const float2* wur = (const float2*)(wti + (size_t)col * 2048) + half * 512;
    const float*  wo  = w_o + o * 1024 + half * 512;

    float4 au = make_float4(0.f,0.f,0.f,0.f);
    float4 ar = make_float4(0.f,0.f,0.f,0.f);
    float4 ao = make_float4(0.f,0.f,0.f,0.f);

    // chunk c covers s_local = c*4 + r ; th covers b = (lane&15)*4 .. +3
    #define CHUNK(c, DO_O)                                                        \
    {                                                                             \
        float4 th4 = *(const float4*)(thbase + (c) * 256 + (lane << 2));          \
        float2 w2  = wur[((c) << 2) + r];                                         \
        au.x = fmaf(th4.x, w2.x, au.x); au.y = fmaf(th4.y, w2.x, au.y);           \
        au.z = fmaf(th4.z, w2.x, au.z); au.w = fmaf(th4.w, w2.x, au.w);           \
        ar.x = fmaf(th4.x, w2.y, ar.x); ar.y = fmaf(th4.y, w2.y, ar.y);           \
        ar.z = fmaf(th4.z, w2.y, ar.z); ar.w = fmaf(th4.w, w2.y, ar.w);           \
        if (DO_O) {                                                               \
            float wv = wo[((c) << 2) + r];                                        \
            ao.x = fmaf(th4.x, wv, ao.x); ao.y = fmaf(th4.y, wv, ao.y);           \
            ao.z = fmaf(th4.z, wv, ao.z); ao.w = fmaf(th4.w, wv, ao.w);           \
        }                                                                         \
    }

    int c = 0;
    #pragma unroll 4
    for (; c < oc0; ++c)        CHUNK(c, false);
    #pragma unroll 4
    for (; c < oc0 + 16; ++c)   CHUNK(c, true);
    #pragma unroll 4
    for (; c < 128; ++c)        CHUNK(c, false);
    #undef CHUNK

    // in-wave reduction over the 4 s-residues -> lanes 0..15 hold b-groups
    red4(au); red4(ar); red4(ao);

    __shared__ float lds[8][2][64];
    if (lane < 16) {
        ((float4*)&lds[wib][0][0])[lane] = au;
        ((float4*)&lds[wib][1][0])[lane] = ar;
    }
    __syncthreads();

    // gate math + h update: done by half-0 wave of each column
    if (half == 0 && lane < 16 && t < TSTEPS) {
        float4 pu = au, pr = ar;
        float4 qu = ((float4*)&lds[wib + 4][0][0])[lane];
        float4 qr = ((float4*)&lds[wib + 4][1][0])[lane];
        pu.x += qu.x; pu.y += qu.y; pu.z += qu.z; pu.w += qu.w;
        pr.x += qr.x; pr.y += qr.y; pr.z += qr.z; pr.w += qr.w;
        float bu = b_u[col], br = b_r[col];

        int idx = col * 64 + lane * 4;
        float4 h4 = *(float4*)(h + idx);
        float hn[4]; float pua[4] = {pu.x,pu.y,pu.z,pu.w};
        float pra[4] = {pr.x,pr.y,pr.z,pr.w};
        float ha[4]  = {h4.x,h4.y,h4.z,h4.w};
        float tha[4];
        #pragma unroll
        for (int j = 0; j < 4; ++j) {
            float u  = 1.0f / (1.0f + expf(-(pua[j] + bu)));
            float rr = tanhf(pra[j] + br);
            hn[j]  = u * ha[j] + (1.0f - u) * rr;
            tha[j] = tanhf(hn[j]);
        }
        *(float4*)(h + idx)   = make_float4(hn[0], hn[1], hn[2], hn[3]);
        *(float4*)(thn + idx) = make_float4(tha[0], tha[1], tha[2], tha[3]);
    }

    // output-projection partials -> err[t-1]
    if (t >= 1 && lane < 16) {
        float av[4] = {ao.x, ao.y, ao.z, ao.w};
        const float* xrow = x + (size_t)(t - 1) * (64 * 128);
        if (half == 0 && (col & 7) == 0) {
            float bo = b_o[o];
            #pragma unroll
            for (int j = 0; j < 4; ++j)
                av[j] += bo - xrow[(lane * 4 + j) * 128 + o];
        }
        float* orow = out + (size_t)(t - 1) * (64 * 128);
        #pragma unroll
        for (int j = 0; j < 4; ++j)
            atomicAdd(orow + (lane * 4 + j) * 128 + o, av[j]);
    }
}

extern "C" void kernel_launch(void* const* d_in, const int* in_sizes, int n_in,
                              void* d_out, int out_size, void* d_ws, size_t ws_size,
                              hipStream_t stream)
{
    const float* x      = (const float*)d_in[0];
    const float* h_init = (const float*)d_in[1];
    const float* w_o    = (const float*)d_in[2];
    const float* b_o    = (const float*)d_in[3];
    const float* w_u    = (const float*)d_in[4];
    const float* b_u    = (const float*)d_in[5];
    const float* w_r    = (const float*)d_in[6];
    const float* b_r    = (const float*)d_in[7];
    float* out = (float*)d_out;
    float* ws  = (float*)d_ws;

    ugrnn_setup<<<512, 256, 0, stream>>>(h_init, w_u, w_r, ws, out);
    for (int t = 0; t <= TSTEPS; ++t)
        ugrnn_step<<<256, 512, 0, stream>>>(x, w_o, b_o, b_u, b_r, ws, out, t);
}